// Round 4
// baseline (471.520 us; speedup 1.0000x reference)
//
#include <hip/hip_runtime.h>

// Problem constants (match reference setup_inputs)
#define B_   1024
#define C_   200
#define L_   3
#define DIM_ 512
#define S_   (C_ + 1)   // 201 output rows per batch

// Sequential-write design: one 256-thread block per batch b. The block walks
// s = 0..200 IN ORDER, so each block emits one 402 KB purely-sequential HBM
// write stream (same shape as fillBufferAligned, which sustains 6.3 TB/s).
// Waves 0-1 (half=0) take even-ish rows, waves 2-3 odd rows, so the block's
// instantaneous write window is a contiguous 4 KB. W/pe rows are re-read per
// row but are L2-resident (1.65 GB of TCC hits total ~= 48 us, overlapped).

typedef float f4 __attribute__((ext_vector_type(4)));

__global__ __launch_bounds__(256) void GSE_84722524880902_kernel(
    const float* __restrict__ x,        // [B, C]
    const float* __restrict__ W,        // [C, L, DIM]
    const float* __restrict__ cls_tok,  // [1, 1, DIM]
    const float* __restrict__ pe,       // [C+1, DIM]
    float* __restrict__ out)            // [B, C+1, DIM]
{
    const int b    = blockIdx.x;
    const int lane = threadIdx.x & 127;                               // f4 lane over DIM_
    const int half = __builtin_amdgcn_readfirstlane(threadIdx.x >> 7); // wave-uniform 0/1
    const int d    = lane << 2;

    f4* const outb = (f4*)(out + b * (S_ * DIM_)) + lane;
    const float* const xb = x + b * C_;

    if (half == 0) {
        // row s=0: cls_token + pe[0]
        const f4 cv = *(const f4*)(cls_tok + d);
        const f4 p0 = *(const f4*)(pe + d);
        f4 r;
        r.x = cv.x + p0.x;
        r.y = cv.y + p0.y;
        r.z = cv.z + p0.z;
        r.w = cv.w + p0.w;
        outb[0] = r;
    }

    // rows 1..200: half=0 -> s=1,3,..,199 ; half=1 -> s=2,4,..,200
    #pragma unroll 2
    for (int i = 0; i < 100; ++i) {
        const int s = 1 + 2 * i + half;   // scalar (half is SGPR)
        const int c = s - 1;
        // edge-replicate pad: clamp window into [0, C-1]
        const int cm = (c > 0)      ? c - 1 : 0;
        const int cp = (c < C_ - 1) ? c + 1 : C_ - 1;

        // scalar x window (SMEM path, L1/L2-resident)
        const float w0 = xb[cm];
        const float w1 = xb[c];
        const float w2 = xb[cp];

        // W row + pe row: L2-resident vector loads
        const float* wrow = W + c * (L_ * DIM_) + d;
        const f4 a0  = *(const f4*)(wrow + 0 * DIM_);
        const f4 a1  = *(const f4*)(wrow + 1 * DIM_);
        const f4 a2  = *(const f4*)(wrow + 2 * DIM_);
        const f4 pev = *(const f4*)(pe + s * DIM_ + d);

        f4 r;
        r.x = fmaf(w0, a0.x, fmaf(w1, a1.x, fmaf(w2, a2.x, pev.x)));
        r.y = fmaf(w0, a0.y, fmaf(w1, a1.y, fmaf(w2, a2.y, pev.y)));
        r.z = fmaf(w0, a0.z, fmaf(w1, a1.z, fmaf(w2, a2.z, pev.z)));
        r.w = fmaf(w0, a0.w, fmaf(w1, a1.w, fmaf(w2, a2.w, pev.w)));

        outb[s * (DIM_ / 4)] = r;         // sequential stream within block
    }
}

extern "C" void kernel_launch(void* const* d_in, const int* in_sizes, int n_in,
                              void* d_out, int out_size, void* d_ws, size_t ws_size,
                              hipStream_t stream) {
    const float* x       = (const float*)d_in[0];   // [B, C]
    const float* W       = (const float*)d_in[1];   // [C, L, DIM]
    const float* cls_tok = (const float*)d_in[2];   // [1, 1, DIM]
    const float* pe      = (const float*)d_in[3];   // [C+1, DIM]
    float* out           = (float*)d_out;           // [B, C+1, DIM]

    GSE_84722524880902_kernel<<<B_, 256, 0, stream>>>(x, W, cls_tok, pe, out);
}

// Round 5
// 417.081 us; speedup vs baseline: 1.1305x; 1.1305x over previous
//
#include <hip/hip_runtime.h>

// Problem constants (match reference setup_inputs)
#define B_   1024
#define C_   200
#define L_   3
#define DIM_ 512
#define S_   (C_ + 1)   // 201 output rows per batch

// Channel-pair design: one 256-thread block owns channels (2i, 2i+1) and a
// group of NB_ batches. tid>>7 selects the channel within the pair, so each
// iteration the block writes rows (b,s) and (b,s+1) = 4 KB CONTIGUOUS —
// matching fillBufferAligned's per-block write granule (it sustains 6.2 TB/s
// with 4 KB granules). W/pe stay register-hoisted and reused NB_ times.
#define NB_       16
#define NCP_      (C_ / 2)          // 100 channel pairs
#define NBG_      (B_ / NB_)        // 64 batch groups
#define NBLK_C_   (NCP_ * NBG_)     // 6400 conv blocks
#define NBLK_CLS_ NBG_              // 64 cls blocks

typedef float f4 __attribute__((ext_vector_type(4)));

__global__ __launch_bounds__(256) void GSE_84722524880902_kernel(
    const float* __restrict__ x,        // [B, C]
    const float* __restrict__ W,        // [C, L, DIM]
    const float* __restrict__ cls_tok,  // [1, 1, DIM]
    const float* __restrict__ pe,       // [C+1, DIM]
    float* __restrict__ out)            // [B, C+1, DIM]
{
    const int lane = threadIdx.x & 127;                                // f4 lane over DIM_
    const int cc   = __builtin_amdgcn_readfirstlane(threadIdx.x >> 7); // wave-uniform 0/1
    const int d    = lane << 2;
    const int blk  = blockIdx.x;

    if (blk < NBLK_C_) {
        // consecutive blocks -> consecutive c-pairs within one batch group:
        // co-scheduled blocks tile a contiguous region of the output.
        const int cpi = blk % NCP_;
        const int bg  = blk / NCP_;
        const int c   = 2 * cpi + cc;     // SGPR channel index
        const int s   = c + 1;

        // edge-replicate pad: clamp window into [0, C-1]
        const int cm  = (c > 0)      ? c - 1 : 0;
        const int cp  = (c < C_ - 1) ? c + 1 : C_ - 1;

        // Hoisted per-block context: pe row + 3 W sub-rows (reused NB_ times)
        const f4 pev = *(const f4*)(pe + s * DIM_ + d);
        const float* wrow = W + c * (L_ * DIM_) + d;
        const f4 a0 = *(const f4*)(wrow + 0 * DIM_);
        const f4 a1 = *(const f4*)(wrow + 1 * DIM_);
        const f4 a2 = *(const f4*)(wrow + 2 * DIM_);

        const float* xb = x + (bg * NB_) * C_;
        f4* op = (f4*)(out + ((bg * NB_) * S_ + s) * DIM_) + lane;

        #pragma unroll 4
        for (int i = 0; i < NB_; ++i) {
            // scalar x window (SMEM path: c is SGPR, xb advances uniformly)
            const float w0 = xb[cm];
            const float w1 = xb[c];
            const float w2 = xb[cp];
            f4 r;
            r.x = fmaf(w0, a0.x, fmaf(w1, a1.x, fmaf(w2, a2.x, pev.x)));
            r.y = fmaf(w0, a0.y, fmaf(w1, a1.y, fmaf(w2, a2.y, pev.y)));
            r.z = fmaf(w0, a0.z, fmaf(w1, a1.z, fmaf(w2, a2.z, pev.z)));
            r.w = fmaf(w0, a0.w, fmaf(w1, a1.w, fmaf(w2, a2.w, pev.w)));
            __builtin_nontemporal_store(r, op);   // block writes 4 KB contiguous
            xb += C_;                             // next batch
            op += S_ * (DIM_ / 4);
        }
    } else {
        // cls rows: out[b, 0, :] = cls_token + pe[0]  (2 MB total, negligible)
        const int bg   = blk - NBLK_C_;
        const int bsub = threadIdx.x >> 7;
        const int b0   = bg * NB_ + bsub;

        const f4 pev = *(const f4*)(pe + d);
        const f4 cv  = *(const f4*)(cls_tok + d);
        f4 r;
        r.x = cv.x + pev.x;
        r.y = cv.y + pev.y;
        r.z = cv.z + pev.z;
        r.w = cv.w + pev.w;

        f4* op = (f4*)(out + b0 * S_ * DIM_) + lane;
        #pragma unroll
        for (int i = 0; i < NB_ / 2; ++i) {
            __builtin_nontemporal_store(r, op);
            op += 2 * S_ * (DIM_ / 4);
        }
    }
}

extern "C" void kernel_launch(void* const* d_in, const int* in_sizes, int n_in,
                              void* d_out, int out_size, void* d_ws, size_t ws_size,
                              hipStream_t stream) {
    const float* x       = (const float*)d_in[0];   // [B, C]
    const float* W       = (const float*)d_in[1];   // [C, L, DIM]
    const float* cls_tok = (const float*)d_in[2];   // [1, 1, DIM]
    const float* pe      = (const float*)d_in[3];   // [C+1, DIM]
    float* out           = (float*)d_out;           // [B, C+1, DIM]

    const int grid = NBLK_C_ + NBLK_CLS_;           // 6464 blocks of 256
    GSE_84722524880902_kernel<<<grid, 256, 0, stream>>>(x, W, cls_tok, pe, out);
}

// Round 6
// 407.720 us; speedup vs baseline: 1.1565x; 1.0230x over previous
//
#include <hip/hip_runtime.h>

// Problem constants (match reference setup_inputs)
#define B_   1024
#define C_   200
#define L_   3
#define DIM_ 512
#define S_   (C_ + 1)   // 201 output rows per batch

// Best-measured variant (R1, 407.6 us): one 256-thread block owns one channel
// c and NB_=16 batches. 128 lanes cover DIM_ as float4; tid>>7 picks one of 2
// concurrent batches; unrolled loop covers the rest. W row + pe row are loaded
// ONCE per block and reused for all NB_ output rows. Kernel-attributable time
// sits at the output-write floor (~421.5 MB mandatory write); residual dur_us
// is harness-invariant (poison fill ~267 us + reset dispatch train).
#define NB_       16
#define NGRP_     (B_ / NB_)        // 64 batch groups
#define NBLK_C_   (C_ * NGRP_)      // 12800 conv blocks
#define NBLK_CLS_ NGRP_             // 64 cls blocks

typedef float f4 __attribute__((ext_vector_type(4)));

__global__ __launch_bounds__(256) void GSE_84722524880902_kernel(
    const float* __restrict__ x,        // [B, C]
    const float* __restrict__ W,        // [C, L, DIM]
    const float* __restrict__ cls_tok,  // [1, 1, DIM]
    const float* __restrict__ pe,       // [C+1, DIM]
    float* __restrict__ out)            // [B, C+1, DIM]
{
    const int lane = threadIdx.x & 127;   // float4 lane over DIM_
    const int bsub = threadIdx.x >> 7;    // 0/1: two batches in flight
    const int d    = lane << 2;
    const int blk  = blockIdx.x;

    if (blk < NBLK_C_) {
        // c fast-varying across blocks: consecutive blocks write consecutive
        // output rows within a batch and read overlapping x cache lines.
        const int c  = blk % C_;
        const int bg = blk / C_;
        const int b0 = bg * NB_ + bsub;
        const int s  = c + 1;

        // edge-replicate pad: window indices clamp into [0, C-1]
        const int cm = (c > 0)      ? c - 1 : 0;
        const int cp = (c < C_ - 1) ? c + 1 : C_ - 1;

        // Hoisted per-block context: pe row + 3 W sub-rows (reused NB_ times)
        const f4 pev = *(const f4*)(pe + s * DIM_ + d);
        const float* wrow = W + c * (L_ * DIM_) + d;
        const f4 a0 = *(const f4*)(wrow + 0 * DIM_);
        const f4 a1 = *(const f4*)(wrow + 1 * DIM_);
        const f4 a2 = *(const f4*)(wrow + 2 * DIM_);

        const float* xb = x + b0 * C_;
        f4* op = (f4*)(out + (b0 * S_ + s) * DIM_) + lane;

        #pragma unroll
        for (int i = 0; i < NB_ / 2; ++i) {
            // wave-uniform scalar loads (L2-resident, broadcast)
            const float w0 = xb[cm];
            const float w1 = xb[c];
            const float w2 = xb[cp];
            f4 r;
            r.x = fmaf(w0, a0.x, fmaf(w1, a1.x, fmaf(w2, a2.x, pev.x)));
            r.y = fmaf(w0, a0.y, fmaf(w1, a1.y, fmaf(w2, a2.y, pev.y)));
            r.z = fmaf(w0, a0.z, fmaf(w1, a1.z, fmaf(w2, a2.z, pev.z)));
            r.w = fmaf(w0, a0.w, fmaf(w1, a1.w, fmaf(w2, a2.w, pev.w)));
            __builtin_nontemporal_store(r, op);
            xb += 2 * C_;                 // advance 2 batches
            op += 2 * S_ * (DIM_ / 4);
        }
    } else {
        // cls rows: out[b, 0, :] = cls_token + pe[0]  (same value for all b)
        const int bg = blk - NBLK_C_;
        const int b0 = bg * NB_ + bsub;

        const f4 pev = *(const f4*)(pe + d);
        const f4 cv  = *(const f4*)(cls_tok + d);
        f4 r;
        r.x = cv.x + pev.x;
        r.y = cv.y + pev.y;
        r.z = cv.z + pev.z;
        r.w = cv.w + pev.w;

        f4* op = (f4*)(out + b0 * S_ * DIM_) + lane;
        #pragma unroll
        for (int i = 0; i < NB_ / 2; ++i) {
            __builtin_nontemporal_store(r, op);
            op += 2 * S_ * (DIM_ / 4);
        }
    }
}

extern "C" void kernel_launch(void* const* d_in, const int* in_sizes, int n_in,
                              void* d_out, int out_size, void* d_ws, size_t ws_size,
                              hipStream_t stream) {
    const float* x       = (const float*)d_in[0];   // [B, C]
    const float* W       = (const float*)d_in[1];   // [C, L, DIM]
    const float* cls_tok = (const float*)d_in[2];   // [1, 1, DIM]
    const float* pe      = (const float*)d_in[3];   // [C+1, DIM]
    float* out           = (float*)d_out;           // [B, C+1, DIM]

    const int grid = NBLK_C_ + NBLK_CLS_;           // 12864 blocks of 256
    GSE_84722524880902_kernel<<<grid, 256, 0, stream>>>(x, W, cls_tok, pe, out);
}